// Round 7
// baseline (1606.562 us; speedup 1.0000x reference)
//
#include <hip/hip_runtime.h>
#include <hip/hip_bf16.h>

#define T_TOKENS 16384
#define HID 1024
#define NEXP 8
#define INTER 3584
#define PAIRS (2*T_TOKENS)
#define PAD_MAX (PAIRS + NEXP*128)   // 33792, multiple of 128

using f32x4    = __attribute__((ext_vector_type(4))) float;
using bfrag    = __attribute__((ext_vector_type(8))) short;
using float4_t = __attribute__((ext_vector_type(4))) float;
using ushort8_t = __attribute__((ext_vector_type(8))) unsigned short;

__device__ inline unsigned short f2bf(float f){
    unsigned u = __float_as_uint(f);
    u += 0x7FFFu + ((u >> 16) & 1u);          // RNE
    return (unsigned short)(u >> 16);
}

// async global -> LDS, 16B per lane, dest = ldsbase + lane*16 (linear)
__device__ inline void gload16(const unsigned short* g, unsigned short* l){
    __builtin_amdgcn_global_load_lds(
        (const __attribute__((address_space(1))) void*)g,
        (__attribute__((address_space(3))) void*)l, 16, 0, 0);
}

// barrier with counted vmcnt: my oldest 8 staging loads done, newer 8 stay in flight
#define BAR_VM8() asm volatile("s_waitcnt vmcnt(8)\n\ts_barrier" ::: "memory")
#define BAR_VM0() asm volatile("s_waitcnt vmcnt(0)\n\ts_barrier" ::: "memory")
#define BAR_PLAIN() asm volatile("s_barrier" ::: "memory")

// bijective XCD swizzle (m204): contiguous grid chunk per XCD
__device__ inline int xcd_swz(int flat, int nwg){
    int q = nwg >> 3, r = nwg & 7;
    int xcd = flat & 7, idx = flat >> 3;
    return (xcd < r ? xcd*(q+1) : r*(q+1) + (xcd - r)*q) + idx;
}

// supertile decode: sw -> (mtile, panel). Supertile = STM M-tiles x nP panels,
// panel-major inside, so an XCD's contiguous sw chunk keeps STM*128 A-rows
// L2-resident while sweeping panels.
__device__ inline void st_decode(int sw, int nM, int nP, int STM,
                                 int& mt, int& p){
    int stSize = STM * nP;
    int st = sw / stSize;
    int rem = sw - st * stSize;
    int base = st * STM;
    int stM = (base + STM <= nM) ? STM : (nM - base);
    p  = rem / stM;
    mt = base + (rem - p * stM);
}

// ---------------- f32 -> bf16 bulk conversion ----------------
__global__ __launch_bounds__(256) void conv_bf16_kernel(
    const float* __restrict__ in, unsigned short* __restrict__ out, int n)
{
    int i0 = (blockIdx.x * 256 + threadIdx.x) * 8;
    int stride = gridDim.x * 256 * 8;
    for (int i = i0; i < n; i += stride){
        float4_t a = *reinterpret_cast<const float4_t*>(in + i);
        float4_t b = *reinterpret_cast<const float4_t*>(in + i + 4);
        ushort8_t o;
        o[0]=f2bf(a.x); o[1]=f2bf(a.y); o[2]=f2bf(a.z); o[3]=f2bf(a.w);
        o[4]=f2bf(b.x); o[5]=f2bf(b.y); o[6]=f2bf(b.z); o[7]=f2bf(b.w);
        *reinterpret_cast<ushort8_t*>(out + i) = o;
    }
}

// ---------------- router ----------------
__global__ __launch_bounds__(256) void router_kernel(
    const float* __restrict__ x, const float* __restrict__ gw,
    int* __restrict__ topk_idx, float* __restrict__ topk_w,
    int* __restrict__ counts)
{
    int wave = threadIdx.x >> 6;
    int lane = threadIdx.x & 63;
    int t = blockIdx.x * 4 + wave;

    float acc[NEXP];
#pragma unroll
    for (int e = 0; e < NEXP; ++e) acc[e] = 0.f;

    const float* xr = x + (size_t)t * HID;
    for (int hb = 0; hb < HID; hb += 64){
        float xv = xr[hb + lane];
#pragma unroll
        for (int e = 0; e < NEXP; ++e)
            acc[e] += xv * gw[e * HID + hb + lane];
    }
#pragma unroll
    for (int e = 0; e < NEXP; ++e){
#pragma unroll
        for (int s = 32; s > 0; s >>= 1)
            acc[e] += __shfl_xor(acc[e], s, 64);
    }
    if (lane == 0){
        int e0 = 0; float m0 = acc[0];
#pragma unroll
        for (int e = 1; e < NEXP; ++e) if (acc[e] > m0){ m0 = acc[e]; e0 = e; }
        int e1 = -1; float m1 = -1e30f;
#pragma unroll
        for (int e = 0; e < NEXP; ++e) if (e != e0 && acc[e] > m1){ m1 = acc[e]; e1 = e; }
        float p1 = __expf(m1 - m0);
        float inv = 1.f / (1.f + p1);
        topk_idx[2*t]   = e0;
        topk_idx[2*t+1] = e1;
        topk_w[2*t]   = inv;
        topk_w[2*t+1] = p1 * inv;
        atomicAdd(&counts[e0], 1);
        atomicAdd(&counts[e1], 1);
    }
}

// ---------------- prefix scan with 128-row padding ----------------
__global__ void scan_kernel(const int* __restrict__ counts, int* __restrict__ offp)
{
    if (threadIdx.x == 0 && blockIdx.x == 0){
        int s = 0;
        for (int e = 0; e < NEXP; ++e){
            offp[e] = s;
            s += (counts[e] + 127) & ~127;
        }
        offp[NEXP] = s;
    }
}

__global__ __launch_bounds__(128) void padfill_kernel(
    const int* __restrict__ counts, const int* __restrict__ offp,
    int* __restrict__ pair_token, float* __restrict__ pair_w)
{
    int e = blockIdx.x;
    int base = offp[e];
    int aligned = offp[e+1] - base;
    for (int s = counts[e] + threadIdx.x; s < aligned; s += 128){
        pair_token[base + s] = (base + s) & (T_TOKENS - 1);
        pair_w[base + s] = 0.f;
    }
}

__global__ __launch_bounds__(256) void scatter_kernel(
    const int* __restrict__ topk_idx, const float* __restrict__ topk_w,
    const int* __restrict__ offp, int* __restrict__ cursors,
    int* __restrict__ pair_token, float* __restrict__ pair_w,
    int* __restrict__ pair_pos)
{
    int t = blockIdx.x * 256 + threadIdx.x;
#pragma unroll
    for (int k = 0; k < 2; ++k){
        int e = topk_idx[2*t + k];
        int slot = atomicAdd(&cursors[e], 1);
        int p = offp[e] + slot;
        pair_token[p] = t;
        pair_w[p] = topk_w[2*t + k];
        pair_pos[2*t + k] = p;
    }
}

// ---------------- fused w1/w3 GEMM + SwiGLU -> act (bf16) ----------------
// M 128 x N 64 (h & u), BK=64, double-buffered, counted vmcnt, swizzled LDS,
// L2 supertile: 8 M-tiles resident across all panels
__global__ __launch_bounds__(256) void gemm_act_kernel(
    const unsigned short* __restrict__ xb,
    const unsigned short* __restrict__ w1b,
    const unsigned short* __restrict__ w3b,
    const int* __restrict__ offp,
    const int* __restrict__ pair_token, const float* __restrict__ pair_w,
    unsigned short* __restrict__ act, int r0)
{
    int nP = gridDim.x, nM = gridDim.y;
    int sw = xcd_swz(blockIdx.y * nP + blockIdx.x, nP * nM);
    int mt, p;
    st_decode(sw, nM, nP, 8, mt, p);
    int by = mt, bx = p;

    int R = r0 + by * 128;
    if (R >= offp[NEXP]) return;
    int e = 0;
    while (offp[e+1] <= R) ++e;
    int icol0 = bx * 64;

    __shared__ alignas(16) unsigned short As0[128*64], As1[128*64];
    __shared__ alignas(16) unsigned short B10[64*64],  B11[64*64];
    __shared__ alignas(16) unsigned short B30[64*64],  B31[64*64];
    __shared__ int   toks[128];
    __shared__ float pws[128];

    int tid = threadIdx.x;
    if (tid < 128){
        toks[tid] = pair_token[R + tid];
        pws[tid]  = pair_w[R + tid];
    }
    __syncthreads();

    int w = tid >> 6, lane = tid & 63;
    int wm = w >> 1, wn = w & 1;
    int lr = lane >> 3;
    int l15 = lane & 15;
    int swz8 = ((lane & 7) ^ lr) * 8;          // inverse-swizzled source chunk

    size_t asrc[4];
#pragma unroll
    for (int i = 0; i < 4; ++i)
        asrc[i] = (size_t)toks[w*32 + i*8 + lr] * HID + swz8;

    const unsigned short* w1e = w1b + (size_t)e * INTER * HID;
    const unsigned short* w3e = w3b + (size_t)e * INTER * HID;
    size_t bsrc[2];
#pragma unroll
    for (int i = 0; i < 2; ++i)
        bsrc[i] = (size_t)(icol0 + w*16 + i*8 + lr) * HID + swz8;

    // swizzled read columns (shorts): ((kk*4 + lane>>4) ^ (row&7)) * 8, row&7 == lane&7
    int ccol[2];
#pragma unroll
    for (int kk = 0; kk < 2; ++kk)
        ccol[kk] = (((kk*4 + (lane >> 4)) ^ (lane & 7)) * 8);

    f32x4 acc_h[4][2], acc_u[4][2];
#pragma unroll
    for (int m = 0; m < 4; ++m)
#pragma unroll
        for (int n = 0; n < 2; ++n){
            acc_h[m][n] = (f32x4){0.f,0.f,0.f,0.f};
            acc_u[m][n] = (f32x4){0.f,0.f,0.f,0.f};
        }

    // exactly 8 gload16 per thread per stage
    auto stageT = [&](unsigned short* As, unsigned short* B1s, unsigned short* B3s, int t){
        int k0 = t * 64;
#pragma unroll
        for (int i = 0; i < 4; ++i) gload16(xb  + asrc[i] + k0, As  + (w*32 + i*8)*64);
#pragma unroll
        for (int i = 0; i < 2; ++i) gload16(w1e + bsrc[i] + k0, B1s + (w*16 + i*8)*64);
#pragma unroll
        for (int i = 0; i < 2; ++i) gload16(w3e + bsrc[i] + k0, B3s + (w*16 + i*8)*64);
    };

    auto computeT = [&](const unsigned short* As, const unsigned short* B1s, const unsigned short* B3s){
        __builtin_amdgcn_s_setprio(1);
#pragma unroll
        for (int kk = 0; kk < 2; ++kk){
            int cc = ccol[kk];
            bfrag a[4];
#pragma unroll
            for (int m = 0; m < 4; ++m)
                a[m] = *reinterpret_cast<const bfrag*>(&As[(wm*64 + m*16 + l15)*64 + cc]);
#pragma unroll
            for (int n = 0; n < 2; ++n){
                bfrag b1 = *reinterpret_cast<const bfrag*>(&B1s[(wn*32 + n*16 + l15)*64 + cc]);
                bfrag b3 = *reinterpret_cast<const bfrag*>(&B3s[(wn*32 + n*16 + l15)*64 + cc]);
#pragma unroll
                for (int m = 0; m < 4; ++m){
                    acc_h[m][n] = __builtin_amdgcn_mfma_f32_16x16x32_bf16(a[m], b1, acc_h[m][n], 0, 0, 0);
                    acc_u[m][n] = __builtin_amdgcn_mfma_f32_16x16x32_bf16(a[m], b3, acc_u[m][n], 0, 0, 0);
                }
            }
        }
        __builtin_amdgcn_s_setprio(0);
    };

    const int NT = HID / 64;   // 16 (even)
    stageT(As0, B10, B30, 0);
    stageT(As1, B11, B31, 1);
#pragma unroll 1
    for (int t = 0; t < NT - 2; t += 2){
        BAR_VM8();                       // stage(t) landed; stage(t+1) in flight
        computeT(As0, B10, B30);
        BAR_PLAIN();                     // all waves done reading buf0
        stageT(As0, B10, B30, t + 2);
        BAR_VM8();                       // stage(t+1) landed; stage(t+2) in flight
        computeT(As1, B11, B31);
        BAR_PLAIN();
        stageT(As1, B11, B31, t + 3);
    }
    BAR_VM8();
    computeT(As0, B10, B30);             // tile NT-2
    BAR_VM0();
    computeT(As1, B11, B31);             // tile NT-1

    // epilogue: act = pair_w * silu(h) * u  (bf16)
    size_t arow0 = (size_t)(by * 128) * INTER;
#pragma unroll
    for (int m = 0; m < 4; ++m){
#pragma unroll
        for (int n = 0; n < 2; ++n){
#pragma unroll
            for (int j = 0; j < 4; ++j){
                int rl = wm*64 + m*16 + (lane >> 4)*4 + j;
                float h = acc_h[m][n][j];
                float u = acc_u[m][n][j];
                float v = pws[rl] * h * u / (1.f + __expf(-h));
                int ic = icol0 + wn*32 + n*16 + l15;
                act[arow0 + (size_t)rl * INTER + ic] = f2bf(v);
            }
        }
    }
}

// ---------------- down-proj GEMM: part[row,:] = act[row,:] @ w2[e]^T ----------------
// M 128 x N 128, BK=64, K=INTER, double-buffered, counted vmcnt, swizzled LDS,
// L2 supertile: 4 M-tiles (3.7 MB act) resident across the 8 h-panels.
// NON-ATOMIC: each padded pair row owned by exactly one block.
__global__ __launch_bounds__(256) void gemm2_kernel(
    const unsigned short* __restrict__ act,
    const unsigned short* __restrict__ w2b,
    const int* __restrict__ offp,
    float* __restrict__ part, int r0)
{
    int nP = gridDim.x, nM = gridDim.y;
    int sw = xcd_swz(blockIdx.y * nP + blockIdx.x, nP * nM);
    int mt, p;
    st_decode(sw, nM, nP, 4, mt, p);
    int by = mt, bx = p;

    int R = r0 + by * 128;
    if (R >= offp[NEXP]) return;
    int e = 0;
    while (offp[e+1] <= R) ++e;
    int h0 = bx * 128;

    __shared__ alignas(16) unsigned short As0[128*64], As1[128*64];
    __shared__ alignas(16) unsigned short Bs0[128*64], Bs1[128*64];

    int tid = threadIdx.x;
    int w = tid >> 6, lane = tid & 63;
    int wm = w >> 1, wn = w & 1;
    int lr = lane >> 3;
    int l15 = lane & 15;
    int swz8 = ((lane & 7) ^ lr) * 8;

    const unsigned short* w2e = w2b + (size_t)e * HID * INTER;
    size_t arow0 = (size_t)(by * 128) * INTER;

    size_t asrc[4], bsrc[4];
#pragma unroll
    for (int i = 0; i < 4; ++i){
        asrc[i] = arow0 + (size_t)(w*32 + i*8 + lr) * INTER + swz8;
        bsrc[i] = (size_t)(h0 + w*32 + i*8 + lr) * INTER + swz8;
    }

    int ccol[2];
#pragma unroll
    for (int kk = 0; kk < 2; ++kk)
        ccol[kk] = (((kk*4 + (lane >> 4)) ^ (lane & 7)) * 8);

    f32x4 acc[4][4];
#pragma unroll
    for (int m = 0; m < 4; ++m)
#pragma unroll
        for (int n = 0; n < 4; ++n)
            acc[m][n] = (f32x4){0.f,0.f,0.f,0.f};

    // exactly 8 gload16 per thread per stage
    auto stageT = [&](unsigned short* As, unsigned short* Bs, int t){
        int kc = t * 64;
#pragma unroll
        for (int i = 0; i < 4; ++i) gload16(act + asrc[i] + kc, As + (w*32 + i*8)*64);
#pragma unroll
        for (int i = 0; i < 4; ++i) gload16(w2e + bsrc[i] + kc, Bs + (w*32 + i*8)*64);
    };

    auto computeT = [&](const unsigned short* As, const unsigned short* Bs){
        __builtin_amdgcn_s_setprio(1);
#pragma unroll
        for (int kk = 0; kk < 2; ++kk){
            int cc = ccol[kk];
            bfrag a[4];
#pragma unroll
            for (int m = 0; m < 4; ++m)
                a[m] = *reinterpret_cast<const bfrag*>(&As[(wm*64 + m*16 + l15)*64 + cc]);
#pragma unroll
            for (int n = 0; n < 4; ++n){
                bfrag b = *reinterpret_cast<const bfrag*>(&Bs[(wn*64 + n*16 + l15)*64 + cc]);
#pragma unroll
                for (int m = 0; m < 4; ++m)
                    acc[m][n] = __builtin_amdgcn_mfma_f32_16x16x32_bf16(a[m], b, acc[m][n], 0, 0, 0);
            }
        }
        __builtin_amdgcn_s_setprio(0);
    };

    const int NT = INTER / 64;   // 56 (even)
    stageT(As0, Bs0, 0);
    stageT(As1, Bs1, 1);
#pragma unroll 1
    for (int t = 0; t < NT - 2; t += 2){
        BAR_VM8();
        computeT(As0, Bs0);
        BAR_PLAIN();
        stageT(As0, Bs0, t + 2);
        BAR_VM8();
        computeT(As1, Bs1);
        BAR_PLAIN();
        stageT(As1, Bs1, t + 3);
    }
    BAR_VM8();
    computeT(As0, Bs0);
    BAR_VM0();
    computeT(As1, Bs1);

    // epilogue: plain coalesced stores (16 lanes -> 64B lines), no atomics
    float* prow = part + (size_t)R * HID;
#pragma unroll
    for (int m = 0; m < 4; ++m){
#pragma unroll
        for (int n = 0; n < 4; ++n){
#pragma unroll
            for (int j = 0; j < 4; ++j){
                int rl = wm*64 + m*16 + (lane >> 4)*4 + j;
                int hc = h0 + wn*64 + n*16 + l15;
                prow[(size_t)rl * HID + hc] = acc[m][n][j];
            }
        }
    }
}

// ---------------- combine: out[t,:] = part[p0(t),:] + part[p1(t),:] ----------------
__global__ __launch_bounds__(256) void combine_kernel(
    const float* __restrict__ part, const int* __restrict__ pair_pos,
    float* __restrict__ out)
{
    int idx = blockIdx.x * 256 + threadIdx.x;   // T*128 threads, 8 cols each
    int t = idx >> 7;
    int c = (idx & 127) * 8;
    int p0 = pair_pos[2*t];
    int p1 = pair_pos[2*t + 1];
    const float* r0 = part + (size_t)p0 * HID + c;
    const float* r1 = part + (size_t)p1 * HID + c;
    float4_t a0 = *reinterpret_cast<const float4_t*>(r0);
    float4_t a1 = *reinterpret_cast<const float4_t*>(r0 + 4);
    float4_t b0 = *reinterpret_cast<const float4_t*>(r1);
    float4_t b1 = *reinterpret_cast<const float4_t*>(r1 + 4);
    float4_t o0 = a0 + b0;
    float4_t o1 = a1 + b1;
    float* orow = out + (size_t)t * HID + c;
    *reinterpret_cast<float4_t*>(orow)     = o0;
    *reinterpret_cast<float4_t*>(orow + 4) = o1;
}

extern "C" void kernel_launch(void* const* d_in, const int* in_sizes, int n_in,
                              void* d_out, int out_size, void* d_ws, size_t ws_size,
                              hipStream_t stream)
{
    const float* x  = (const float*)d_in[0];
    const float* gw = (const float*)d_in[1];
    const float* w1 = (const float*)d_in[2];
    const float* w3 = (const float*)d_in[3];
    const float* w2 = (const float*)d_in[4];
    float* out = (float*)d_out;

    char* ws = (char*)d_ws;
    size_t off = 0;
    auto bump = [&](size_t bytes) -> void* {
        void* p = ws + off;
        off = (off + bytes + 255) & ~(size_t)255;
        return p;
    };
    int*   counts     = (int*)bump(32);
    int*   cursors    = (int*)bump(32);
    int*   offp       = (int*)bump(64);
    int*   topk_idx   = (int*)bump((size_t)PAIRS * 4);
    float* topk_w     = (float*)bump((size_t)PAIRS * 4);
    int*   pair_token = (int*)bump((size_t)PAD_MAX * 4);
    float* pair_w     = (float*)bump((size_t)PAD_MAX * 4);
    int*   pair_pos   = (int*)bump((size_t)PAIRS * 4);
    unsigned short* xb  = (unsigned short*)bump((size_t)T_TOKENS * HID * 2);
    unsigned short* w1b = (unsigned short*)bump((size_t)NEXP * INTER * HID * 2);
    unsigned short* w3b = (unsigned short*)bump((size_t)NEXP * INTER * HID * 2);
    unsigned short* w2b = (unsigned short*)bump((size_t)NEXP * HID * INTER * 2);
    float* part = (float*)bump((size_t)PAD_MAX * HID * 4);   // 138.4 MB
    unsigned short* act = (unsigned short*)(ws + off);

    size_t rem = (ws_size > off) ? (ws_size - off) : 0;
    int RC = (int)(rem / ((size_t)INTER * 2));
    RC &= ~127;
    if (RC > PAD_MAX) RC = PAD_MAX;
    if (RC < 128) RC = 128;
    int nchunks = (PAD_MAX + RC - 1) / RC;

    hipMemsetAsync(ws, 0, 1024, stream);

    conv_bf16_kernel<<<2048, 256, 0, stream>>>(x,  xb,  T_TOKENS * HID);
    conv_bf16_kernel<<<2048, 256, 0, stream>>>(w1, w1b, NEXP * INTER * HID);
    conv_bf16_kernel<<<2048, 256, 0, stream>>>(w3, w3b, NEXP * INTER * HID);
    conv_bf16_kernel<<<2048, 256, 0, stream>>>(w2, w2b, NEXP * HID * INTER);

    router_kernel<<<T_TOKENS/4, 256, 0, stream>>>(x, gw, topk_idx, topk_w, counts);
    scan_kernel<<<1, 64, 0, stream>>>(counts, offp);
    padfill_kernel<<<NEXP, 128, 0, stream>>>(counts, offp, pair_token, pair_w);
    scatter_kernel<<<T_TOKENS/256, 256, 0, stream>>>(topk_idx, topk_w, offp, cursors,
                                                     pair_token, pair_w, pair_pos);

    for (int c = 0; c < nchunks; ++c){
        int r0 = c * RC;
        gemm_act_kernel<<<dim3(INTER/64, RC/128), 256, 0, stream>>>(
            xb, w1b, w3b, offp, pair_token, pair_w, act, r0);
        gemm2_kernel<<<dim3(HID/128, RC/128), 256, 0, stream>>>(
            act, w2b, offp, part, r0);
    }
    combine_kernel<<<T_TOKENS*128/256, 256, 0, stream>>>(part, pair_pos, out);
}

// Round 8
// 1068.800 us; speedup vs baseline: 1.5031x; 1.5031x over previous
//
#include <hip/hip_runtime.h>
#include <hip/hip_bf16.h>

#define T_TOKENS 16384
#define HID 1024
#define NEXP 8
#define INTER 3584
#define PAIRS (2*T_TOKENS)
#define PAD_MAX (PAIRS + NEXP*128)   // 33792, multiple of 128

using f32x4    = __attribute__((ext_vector_type(4))) float;
using bfrag    = __attribute__((ext_vector_type(8))) short;
using float4_t = __attribute__((ext_vector_type(4))) float;
using ushort8_t = __attribute__((ext_vector_type(8))) unsigned short;

__device__ inline unsigned short f2bf(float f){
    unsigned u = __float_as_uint(f);
    u += 0x7FFFu + ((u >> 16) & 1u);          // RNE
    return (unsigned short)(u >> 16);
}

// async global -> LDS, 16B per lane, dest = ldsbase + lane*16 (linear)
__device__ inline void gload16(const unsigned short* g, unsigned short* l){
    __builtin_amdgcn_global_load_lds(
        (const __attribute__((address_space(1))) void*)g,
        (__attribute__((address_space(3))) void*)l, 16, 0, 0);
}

// barrier with counted vmcnt: my oldest 8 staging loads done, newer 8 stay in flight
#define BAR_VM8() asm volatile("s_waitcnt vmcnt(8)\n\ts_barrier" ::: "memory")
#define BAR_VM0() asm volatile("s_waitcnt vmcnt(0)\n\ts_barrier" ::: "memory")
#define BAR_PLAIN() asm volatile("s_barrier" ::: "memory")

// bijective XCD swizzle (m204): contiguous grid chunk per XCD
__device__ inline int xcd_swz(int flat, int nwg){
    int q = nwg >> 3, r = nwg & 7;
    int xcd = flat & 7, idx = flat >> 3;
    return (xcd < r ? xcd*(q+1) : r*(q+1) + (xcd - r)*q) + idx;
}

// supertile decode: sw -> (mtile, panel). Supertile = STM M-tiles x nP panels,
// panel-major inside, so an XCD's contiguous sw chunk keeps STM*128 A-rows
// L2-resident while sweeping panels.
__device__ inline void st_decode(int sw, int nM, int nP, int STM,
                                 int& mt, int& p){
    int stSize = STM * nP;
    int st = sw / stSize;
    int rem = sw - st * stSize;
    int base = st * STM;
    int stM = (base + STM <= nM) ? STM : (nM - base);
    p  = rem / stM;
    mt = base + (rem - p * stM);
}

// ---------------- f32 -> bf16 bulk conversion ----------------
__global__ __launch_bounds__(256) void conv_bf16_kernel(
    const float* __restrict__ in, unsigned short* __restrict__ out, int n)
{
    int i0 = (blockIdx.x * 256 + threadIdx.x) * 8;
    int stride = gridDim.x * 256 * 8;
    for (int i = i0; i < n; i += stride){
        float4_t a = *reinterpret_cast<const float4_t*>(in + i);
        float4_t b = *reinterpret_cast<const float4_t*>(in + i + 4);
        ushort8_t o;
        o[0]=f2bf(a.x); o[1]=f2bf(a.y); o[2]=f2bf(a.z); o[3]=f2bf(a.w);
        o[4]=f2bf(b.x); o[5]=f2bf(b.y); o[6]=f2bf(b.z); o[7]=f2bf(b.w);
        *reinterpret_cast<ushort8_t*>(out + i) = o;
    }
}

// ---------------- router (NO count atomics) ----------------
__global__ __launch_bounds__(256) void router_kernel(
    const float* __restrict__ x, const float* __restrict__ gw,
    int* __restrict__ topk_idx, float* __restrict__ topk_w)
{
    int wave = threadIdx.x >> 6;
    int lane = threadIdx.x & 63;
    int t = blockIdx.x * 4 + wave;

    float acc[NEXP];
#pragma unroll
    for (int e = 0; e < NEXP; ++e) acc[e] = 0.f;

    const float* xr = x + (size_t)t * HID;
    for (int hb = 0; hb < HID; hb += 64){
        float xv = xr[hb + lane];
#pragma unroll
        for (int e = 0; e < NEXP; ++e)
            acc[e] += xv * gw[e * HID + hb + lane];
    }
#pragma unroll
    for (int e = 0; e < NEXP; ++e){
#pragma unroll
        for (int s = 32; s > 0; s >>= 1)
            acc[e] += __shfl_xor(acc[e], s, 64);
    }
    if (lane == 0){
        int e0 = 0; float m0 = acc[0];
#pragma unroll
        for (int e = 1; e < NEXP; ++e) if (acc[e] > m0){ m0 = acc[e]; e0 = e; }
        int e1 = -1; float m1 = -1e30f;
#pragma unroll
        for (int e = 0; e < NEXP; ++e) if (e != e0 && acc[e] > m1){ m1 = acc[e]; e1 = e; }
        float p1 = __expf(m1 - m0);
        float inv = 1.f / (1.f + p1);
        topk_idx[2*t]   = e0;
        topk_idx[2*t+1] = e1;
        topk_w[2*t]   = inv;
        topk_w[2*t+1] = p1 * inv;
    }
}

// ---------------- histogram: LDS-reduced, 512 global atomics total ----------------
__global__ __launch_bounds__(256) void hist_kernel(
    const int* __restrict__ topk_idx, int* __restrict__ counts)
{
    __shared__ int h[NEXP];
    if (threadIdx.x < NEXP) h[threadIdx.x] = 0;
    __syncthreads();
    int i0 = blockIdx.x * 256 + threadIdx.x;
    for (int i = i0; i < PAIRS; i += gridDim.x * 256)
        atomicAdd(&h[topk_idx[i]], 1);
    __syncthreads();
    if (threadIdx.x < NEXP) atomicAdd(&counts[threadIdx.x], h[threadIdx.x]);
}

// ---------------- prefix scan with 128-row padding ----------------
__global__ void scan_kernel(const int* __restrict__ counts, int* __restrict__ offp)
{
    if (threadIdx.x == 0 && blockIdx.x == 0){
        int s = 0;
        for (int e = 0; e < NEXP; ++e){
            offp[e] = s;
            s += (counts[e] + 127) & ~127;
        }
        offp[NEXP] = s;
    }
}

__global__ __launch_bounds__(128) void padfill_kernel(
    const int* __restrict__ counts, const int* __restrict__ offp,
    int* __restrict__ pair_token, float* __restrict__ pair_w)
{
    int e = blockIdx.x;
    int base = offp[e];
    int aligned = offp[e+1] - base;
    for (int s = counts[e] + threadIdx.x; s < aligned; s += 128){
        pair_token[base + s] = (base + s) & (T_TOKENS - 1);
        pair_w[base + s] = 0.f;
    }
}

// ---------------- scatter: block-batched range reservation ----------------
// 64 blocks x 256 tokens each; 8 reservation atomics per block.
__global__ __launch_bounds__(256) void scatter_kernel(
    const int* __restrict__ topk_idx, const float* __restrict__ topk_w,
    const int* __restrict__ offp, int* __restrict__ cursors,
    int* __restrict__ pair_token, float* __restrict__ pair_w)
{
    __shared__ int hist[NEXP], base[NEXP], lcur[NEXP];
    int tid = threadIdx.x;
    if (tid < NEXP){ hist[tid] = 0; lcur[tid] = 0; }
    __syncthreads();

    int t = blockIdx.x * 256 + tid;
    int e0 = topk_idx[2*t], e1 = topk_idx[2*t + 1];
    atomicAdd(&hist[e0], 1);
    atomicAdd(&hist[e1], 1);
    __syncthreads();

    if (tid < NEXP) base[tid] = atomicAdd(&cursors[tid], hist[tid]);
    __syncthreads();

    int r0 = atomicAdd(&lcur[e0], 1);
    int r1 = atomicAdd(&lcur[e1], 1);
    int p0 = offp[e0] + base[e0] + r0;
    int p1 = offp[e1] + base[e1] + r1;
    pair_token[p0] = t;  pair_w[p0] = topk_w[2*t];
    pair_token[p1] = t;  pair_w[p1] = topk_w[2*t + 1];
}

// ---------------- fused w1/w3 GEMM + SwiGLU -> act (bf16) ----------------
// M 128 x N 64 (h & u), BK=64, double-buffered, counted vmcnt, swizzled LDS,
// L2 supertile: 8 M-tiles resident across all panels
__global__ __launch_bounds__(256) void gemm_act_kernel(
    const unsigned short* __restrict__ xb,
    const unsigned short* __restrict__ w1b,
    const unsigned short* __restrict__ w3b,
    const int* __restrict__ offp,
    const int* __restrict__ pair_token, const float* __restrict__ pair_w,
    unsigned short* __restrict__ act, int r0)
{
    int nP = gridDim.x, nM = gridDim.y;
    int sw = xcd_swz(blockIdx.y * nP + blockIdx.x, nP * nM);
    int mt, p;
    st_decode(sw, nM, nP, 8, mt, p);
    int by = mt, bx = p;

    int R = r0 + by * 128;
    if (R >= offp[NEXP]) return;
    int e = 0;
    while (offp[e+1] <= R) ++e;
    int icol0 = bx * 64;

    __shared__ alignas(16) unsigned short As0[128*64], As1[128*64];
    __shared__ alignas(16) unsigned short B10[64*64],  B11[64*64];
    __shared__ alignas(16) unsigned short B30[64*64],  B31[64*64];
    __shared__ int   toks[128];
    __shared__ float pws[128];

    int tid = threadIdx.x;
    if (tid < 128){
        toks[tid] = pair_token[R + tid];
        pws[tid]  = pair_w[R + tid];
    }
    __syncthreads();

    int w = tid >> 6, lane = tid & 63;
    int wm = w >> 1, wn = w & 1;
    int lr = lane >> 3;
    int l15 = lane & 15;
    int swz8 = ((lane & 7) ^ lr) * 8;          // inverse-swizzled source chunk

    size_t asrc[4];
#pragma unroll
    for (int i = 0; i < 4; ++i)
        asrc[i] = (size_t)toks[w*32 + i*8 + lr] * HID + swz8;

    const unsigned short* w1e = w1b + (size_t)e * INTER * HID;
    const unsigned short* w3e = w3b + (size_t)e * INTER * HID;
    size_t bsrc[2];
#pragma unroll
    for (int i = 0; i < 2; ++i)
        bsrc[i] = (size_t)(icol0 + w*16 + i*8 + lr) * HID + swz8;

    // swizzled read columns (shorts): ((kk*4 + lane>>4) ^ (row&7)) * 8, row&7 == lane&7
    int ccol[2];
#pragma unroll
    for (int kk = 0; kk < 2; ++kk)
        ccol[kk] = (((kk*4 + (lane >> 4)) ^ (lane & 7)) * 8);

    f32x4 acc_h[4][2], acc_u[4][2];
#pragma unroll
    for (int m = 0; m < 4; ++m)
#pragma unroll
        for (int n = 0; n < 2; ++n){
            acc_h[m][n] = (f32x4){0.f,0.f,0.f,0.f};
            acc_u[m][n] = (f32x4){0.f,0.f,0.f,0.f};
        }

    // exactly 8 gload16 per thread per stage
    auto stageT = [&](unsigned short* As, unsigned short* B1s, unsigned short* B3s, int t){
        int k0 = t * 64;
#pragma unroll
        for (int i = 0; i < 4; ++i) gload16(xb  + asrc[i] + k0, As  + (w*32 + i*8)*64);
#pragma unroll
        for (int i = 0; i < 2; ++i) gload16(w1e + bsrc[i] + k0, B1s + (w*16 + i*8)*64);
#pragma unroll
        for (int i = 0; i < 2; ++i) gload16(w3e + bsrc[i] + k0, B3s + (w*16 + i*8)*64);
    };

    auto computeT = [&](const unsigned short* As, const unsigned short* B1s, const unsigned short* B3s){
        __builtin_amdgcn_s_setprio(1);
#pragma unroll
        for (int kk = 0; kk < 2; ++kk){
            int cc = ccol[kk];
            bfrag a[4];
#pragma unroll
            for (int m = 0; m < 4; ++m)
                a[m] = *reinterpret_cast<const bfrag*>(&As[(wm*64 + m*16 + l15)*64 + cc]);
#pragma unroll
            for (int n = 0; n < 2; ++n){
                bfrag b1 = *reinterpret_cast<const bfrag*>(&B1s[(wn*32 + n*16 + l15)*64 + cc]);
                bfrag b3 = *reinterpret_cast<const bfrag*>(&B3s[(wn*32 + n*16 + l15)*64 + cc]);
#pragma unroll
                for (int m = 0; m < 4; ++m){
                    acc_h[m][n] = __builtin_amdgcn_mfma_f32_16x16x32_bf16(a[m], b1, acc_h[m][n], 0, 0, 0);
                    acc_u[m][n] = __builtin_amdgcn_mfma_f32_16x16x32_bf16(a[m], b3, acc_u[m][n], 0, 0, 0);
                }
            }
        }
        __builtin_amdgcn_s_setprio(0);
    };

    const int NT = HID / 64;   // 16 (even)
    stageT(As0, B10, B30, 0);
    stageT(As1, B11, B31, 1);
#pragma unroll 1
    for (int t = 0; t < NT - 2; t += 2){
        BAR_VM8();                       // stage(t) landed; stage(t+1) in flight
        computeT(As0, B10, B30);
        BAR_PLAIN();                     // all waves done reading buf0
        stageT(As0, B10, B30, t + 2);
        BAR_VM8();                       // stage(t+1) landed; stage(t+2) in flight
        computeT(As1, B11, B31);
        BAR_PLAIN();
        stageT(As1, B11, B31, t + 3);
    }
    BAR_VM8();
    computeT(As0, B10, B30);             // tile NT-2
    BAR_VM0();
    computeT(As1, B11, B31);             // tile NT-1

    // epilogue: act = pair_w * silu(h) * u  (bf16)
    size_t arow0 = (size_t)(by * 128) * INTER;
#pragma unroll
    for (int m = 0; m < 4; ++m){
#pragma unroll
        for (int n = 0; n < 2; ++n){
#pragma unroll
            for (int j = 0; j < 4; ++j){
                int rl = wm*64 + m*16 + (lane >> 4)*4 + j;
                float h = acc_h[m][n][j];
                float u = acc_u[m][n][j];
                float v = pws[rl] * h * u / (1.f + __expf(-h));
                int ic = icol0 + wn*32 + n*16 + l15;
                act[arow0 + (size_t)rl * INTER + ic] = f2bf(v);
            }
        }
    }
}

// ---------------- down-proj GEMM: out[tok,:] += act[row,:] @ w2[e]^T ----------------
// M 128 x N 128, BK=64, K=INTER, double-buffered, counted vmcnt, swizzled LDS,
// L2 supertile: 4 M-tiles (3.7 MB act) resident across the 8 h-panels.
__global__ __launch_bounds__(256) void gemm2_kernel(
    const unsigned short* __restrict__ act,
    const unsigned short* __restrict__ w2b,
    const int* __restrict__ offp,
    const int* __restrict__ pair_token,
    float* __restrict__ out, int r0)
{
    int nP = gridDim.x, nM = gridDim.y;
    int sw = xcd_swz(blockIdx.y * nP + blockIdx.x, nP * nM);
    int mt, p;
    st_decode(sw, nM, nP, 4, mt, p);
    int by = mt, bx = p;

    int R = r0 + by * 128;
    if (R >= offp[NEXP]) return;
    int e = 0;
    while (offp[e+1] <= R) ++e;
    int h0 = bx * 128;

    __shared__ alignas(16) unsigned short As0[128*64], As1[128*64];
    __shared__ alignas(16) unsigned short Bs0[128*64], Bs1[128*64];
    __shared__ int toks[128];

    int tid = threadIdx.x;
    if (tid < 128) toks[tid] = pair_token[R + tid];
    __syncthreads();

    int w = tid >> 6, lane = tid & 63;
    int wm = w >> 1, wn = w & 1;
    int lr = lane >> 3;
    int l15 = lane & 15;
    int swz8 = ((lane & 7) ^ lr) * 8;

    const unsigned short* w2e = w2b + (size_t)e * HID * INTER;
    size_t arow0 = (size_t)(by * 128) * INTER;

    size_t asrc[4], bsrc[4];
#pragma unroll
    for (int i = 0; i < 4; ++i){
        asrc[i] = arow0 + (size_t)(w*32 + i*8 + lr) * INTER + swz8;
        bsrc[i] = (size_t)(h0 + w*32 + i*8 + lr) * INTER + swz8;
    }

    int ccol[2];
#pragma unroll
    for (int kk = 0; kk < 2; ++kk)
        ccol[kk] = (((kk*4 + (lane >> 4)) ^ (lane & 7)) * 8);

    f32x4 acc[4][4];
#pragma unroll
    for (int m = 0; m < 4; ++m)
#pragma unroll
        for (int n = 0; n < 4; ++n)
            acc[m][n] = (f32x4){0.f,0.f,0.f,0.f};

    // exactly 8 gload16 per thread per stage
    auto stageT = [&](unsigned short* As, unsigned short* Bs, int t){
        int kc = t * 64;
#pragma unroll
        for (int i = 0; i < 4; ++i) gload16(act + asrc[i] + kc, As + (w*32 + i*8)*64);
#pragma unroll
        for (int i = 0; i < 4; ++i) gload16(w2e + bsrc[i] + kc, Bs + (w*32 + i*8)*64);
    };

    auto computeT = [&](const unsigned short* As, const unsigned short* Bs){
        __builtin_amdgcn_s_setprio(1);
#pragma unroll
        for (int kk = 0; kk < 2; ++kk){
            int cc = ccol[kk];
            bfrag a[4];
#pragma unroll
            for (int m = 0; m < 4; ++m)
                a[m] = *reinterpret_cast<const bfrag*>(&As[(wm*64 + m*16 + l15)*64 + cc]);
#pragma unroll
            for (int n = 0; n < 4; ++n){
                bfrag b = *reinterpret_cast<const bfrag*>(&Bs[(wn*64 + n*16 + l15)*64 + cc]);
#pragma unroll
                for (int m = 0; m < 4; ++m)
                    acc[m][n] = __builtin_amdgcn_mfma_f32_16x16x32_bf16(a[m], b, acc[m][n], 0, 0, 0);
            }
        }
        __builtin_amdgcn_s_setprio(0);
    };

    const int NT = INTER / 64;   // 56 (even)
    stageT(As0, Bs0, 0);
    stageT(As1, Bs1, 1);
#pragma unroll 1
    for (int t = 0; t < NT - 2; t += 2){
        BAR_VM8();
        computeT(As0, Bs0);
        BAR_PLAIN();
        stageT(As0, Bs0, t + 2);
        BAR_VM8();
        computeT(As1, Bs1);
        BAR_PLAIN();
        stageT(As1, Bs1, t + 3);
    }
    BAR_VM8();
    computeT(As0, Bs0);
    BAR_VM0();
    computeT(As1, Bs1);

#pragma unroll
    for (int m = 0; m < 4; ++m){
#pragma unroll
        for (int n = 0; n < 4; ++n){
#pragma unroll
            for (int j = 0; j < 4; ++j){
                int rl = wm*64 + m*16 + (lane >> 4)*4 + j;
                int hc = h0 + wn*64 + n*16 + l15;
                atomicAdd(&out[(size_t)toks[rl] * HID + hc], acc[m][n][j]);
            }
        }
    }
}

extern "C" void kernel_launch(void* const* d_in, const int* in_sizes, int n_in,
                              void* d_out, int out_size, void* d_ws, size_t ws_size,
                              hipStream_t stream)
{
    const float* x  = (const float*)d_in[0];
    const float* gw = (const float*)d_in[1];
    const float* w1 = (const float*)d_in[2];
    const float* w3 = (const float*)d_in[3];
    const float* w2 = (const float*)d_in[4];
    float* out = (float*)d_out;

    char* ws = (char*)d_ws;
    size_t off = 0;
    auto bump = [&](size_t bytes) -> void* {
        void* p = ws + off;
        off = (off + bytes + 255) & ~(size_t)255;
        return p;
    };
    int*   counts     = (int*)bump(32);
    int*   cursors    = (int*)bump(32);
    int*   offp       = (int*)bump(64);
    int*   topk_idx   = (int*)bump((size_t)PAIRS * 4);
    float* topk_w     = (float*)bump((size_t)PAIRS * 4);
    int*   pair_token = (int*)bump((size_t)PAD_MAX * 4);
    float* pair_w     = (float*)bump((size_t)PAD_MAX * 4);
    unsigned short* xb  = (unsigned short*)bump((size_t)T_TOKENS * HID * 2);
    unsigned short* w1b = (unsigned short*)bump((size_t)NEXP * INTER * HID * 2);
    unsigned short* w3b = (unsigned short*)bump((size_t)NEXP * INTER * HID * 2);
    unsigned short* w2b = (unsigned short*)bump((size_t)NEXP * HID * INTER * 2);
    unsigned short* act = (unsigned short*)(ws + off);

    size_t rem = (ws_size > off) ? (ws_size - off) : 0;
    int RC = (int)(rem / ((size_t)INTER * 2));
    RC &= ~127;
    if (RC > PAD_MAX) RC = PAD_MAX;
    if (RC < 128) RC = 128;
    int nchunks = (PAD_MAX + RC - 1) / RC;

    hipMemsetAsync(d_out, 0, (size_t)T_TOKENS * HID * 4, stream);
    hipMemsetAsync(ws, 0, 1024, stream);

    conv_bf16_kernel<<<2048, 256, 0, stream>>>(x,  xb,  T_TOKENS * HID);
    conv_bf16_kernel<<<2048, 256, 0, stream>>>(w1, w1b, NEXP * INTER * HID);
    conv_bf16_kernel<<<2048, 256, 0, stream>>>(w3, w3b, NEXP * INTER * HID);
    conv_bf16_kernel<<<2048, 256, 0, stream>>>(w2, w2b, NEXP * HID * INTER);

    router_kernel<<<T_TOKENS/4, 256, 0, stream>>>(x, gw, topk_idx, topk_w);
    hist_kernel<<<64, 256, 0, stream>>>(topk_idx, counts);
    scan_kernel<<<1, 64, 0, stream>>>(counts, offp);
    padfill_kernel<<<NEXP, 128, 0, stream>>>(counts, offp, pair_token, pair_w);
    scatter_kernel<<<T_TOKENS/256, 256, 0, stream>>>(topk_idx, topk_w, offp, cursors,
                                                     pair_token, pair_w);

    for (int c = 0; c < nchunks; ++c){
        int r0 = c * RC;
        gemm_act_kernel<<<dim3(INTER/64, RC/128), 256, 0, stream>>>(
            xb, w1b, w3b, offp, pair_token, pair_w, act, r0);
        gemm2_kernel<<<dim3(HID/128, RC/128), 256, 0, stream>>>(
            act, w2b, offp, pair_token, out, r0);
    }
}